// Round 8
// baseline (210.428 us; speedup 1.0000x reference)
//
#include <hip/hip_runtime.h>
#include <hip/hip_bf16.h>
#include <math.h>

#define B_    16
#define T1_   64
#define T2_   64
#define D_    1024
#define PROJ_ 512
#define BM    64
#define BKS   128                // K per barrier-step (4 MFMA-k sub-steps)
#define NTS   (D_ / BKS)         // 8 barrier-steps
#define ABUF  16384              // one As buffer: 64 rows * 128 bf16 * 2B

typedef __attribute__((ext_vector_type(8))) short bf16x8;
typedef __attribute__((ext_vector_type(4))) float f32x4;
typedef __attribute__((ext_vector_type(4))) unsigned int u32x4;

// RNE fp32->bf16, no NaN path (inputs are finite)
__device__ __forceinline__ unsigned short f2bf(float f) {
  unsigned int u = __builtin_bit_cast(unsigned int, f);
  u += 0x7FFFu + ((u >> 16) & 1u);
  return (unsigned short)(u >> 16);
}

// tanh(a) = 1 - 2/(exp(2a)+1); v_exp_f32 + v_rcp_f32, ~5 instr, |err|~1e-6
__device__ __forceinline__ float fast_tanh(float a) {
  float t = __builtin_amdgcn_exp2f(a * 2.885390081777927f);  // exp(2a)
  return 1.0f - 2.0f * __builtin_amdgcn_rcpf(t + 1.0f);
}

// ---------------------------------------------------------------------------
// Prep: Wt fragment-ordered bf16. 16B chunk index ((t32*32 + n16)*64 + lane)
// holds W[k][n], n = n16*16 + (lane&15), k = t32*32 + (lane>>4)*8 + j.
// ---------------------------------------------------------------------------
__global__ __launch_bounds__(256) void make_bfrag(
    const float* __restrict__ W, unsigned short* __restrict__ wt) {
  __shared__ float tile[32][33];
  const int t  = blockIdx.x;        // k-step 0..31
  const int np = blockIdx.y;        // n-pair 0..15
  const int tx = threadIdx.x & 31;
  const int ty = threadIdx.x >> 5;  // 0..7
#pragma unroll
  for (int i = 0; i < 4; ++i)
    tile[ty + i * 8][tx] =
        W[(size_t)(t * 32 + ty + i * 8) * PROJ_ + np * 32 + tx];
  __syncthreads();
  if (threadIdx.x < 128) {
    const int sub  = threadIdx.x >> 6;   // 0..1
    const int lane = threadIdx.x & 63;
    const int llo = lane & 15, lhi = lane >> 4;
    unsigned short o[8];
#pragma unroll
    for (int j = 0; j < 8; ++j)
      o[j] = f2bf(tile[lhi * 8 + j][sub * 16 + llo]);
    const int n16 = np * 2 + sub;
    *(u32x4*)(wt + ((size_t)(t * 32 + n16) * 64 + lane) * 8) = *(const u32x4*)o;
  }
}

// ---------------------------------------------------------------------------
// Fused: one (b,t1) group of 64 rows per 512-thread block (8 waves).
// scores = v . tanh(x @ W) via bf16 MFMA -> softmax(64) -> out = attn . x
// wid = 64-col n-slice; wave-tile 64x64, acc[4][4].
// K-loop: BKS=128 per barrier (8 barriers total, 4x fewer than before) —
// amortizes the 2-phase barrier/latency overhead (m233 signature).
// A: reg-staged fp32->bf16 into XOR-swizzled LDS dbuf (byte ^= (row&7)<<4,
//    conflict-free ds_read_b128). B: register frags from L2-resident Wt.
// ---------------------------------------------------------------------------
__global__ __launch_bounds__(512, 4) void fused_kernel(
    const float* __restrict__ x, const unsigned short* __restrict__ wt,
    const float* __restrict__ v, float* __restrict__ out) {
  __shared__ __align__(16) char smem[2 * ABUF];   // As dbuf; epilogue overlays
  float (*sp)[9] = (float(*)[9])smem;             // 64*9 f32 = 2304 B
  float* attn    = (float*)(smem + 2304);         // 256 B
  f32x4* xred    = (f32x4*)(smem + 2560);         // 4 KB

  const int tid  = threadIdx.x;
  const int lane = tid & 63;
  const int wid  = tid >> 6;            // 0..7
  const int llo  = lane & 15, lhi = lane >> 4;
  const int bt   = blockIdx.x;
  const int m0   = bt * BM;

  f32x4 acc[4][4];
#pragma unroll
  for (int mf = 0; mf < 4; ++mf)
#pragma unroll
    for (int nf = 0; nf < 4; ++nf) acc[mf][nf] = (f32x4){0.f, 0.f, 0.f, 0.f};

  // A staging map: thread -> row = tid/8, 16 consecutive k at (tid&7)*16
  const int arow = tid >> 3, akc = (tid & 7) * 16;
  const float* asrc = x + (size_t)(m0 + arow) * D_ + akc;
  // LDS byte offsets for this thread's two 16B writes (swizzled)
  const int wb0 = (arow * 256 + akc * 2)        ^ ((arow & 7) << 4);
  const int wb1 = (arow * 256 + akc * 2 + 16)   ^ ((arow & 7) << 4);

  const u32x4* wt4 = (const u32x4*)wt;  // chunk index (t32*32 + n16)*64 + lane
  const int bbase = (wid * 4) * 64 + lane;

  // ---- prologue: chunk 0 -> As[0]; B(t32=0) -> rb ----
  {
    float4 p0 = *(const float4*)(asrc);
    float4 p1 = *(const float4*)(asrc + 4);
    float4 p2 = *(const float4*)(asrc + 8);
    float4 p3 = *(const float4*)(asrc + 12);
    unsigned short o[16] = {f2bf(p0.x), f2bf(p0.y), f2bf(p0.z), f2bf(p0.w),
                            f2bf(p1.x), f2bf(p1.y), f2bf(p1.z), f2bf(p1.w),
                            f2bf(p2.x), f2bf(p2.y), f2bf(p2.z), f2bf(p2.w),
                            f2bf(p3.x), f2bf(p3.y), f2bf(p3.z), f2bf(p3.w)};
    *(u32x4*)(smem + wb0) = *(const u32x4*)&o[0];
    *(u32x4*)(smem + wb1) = *(const u32x4*)&o[8];
  }
  u32x4 rb[4];
#pragma unroll
  for (int nf = 0; nf < 4; ++nf) rb[nf] = wt4[bbase + nf * 64];
  asm volatile("s_waitcnt lgkmcnt(0)" ::: "memory");
  __builtin_amdgcn_s_barrier();

  // ---- K loop: 8 barrier-steps of 128 k each ----
  for (int T = 0; T < NTS; ++T) {
    char* asr = smem + (T & 1) * ABUF;
    // issue next chunk's global loads (whole step to cover latency)
    float4 sa0, sa1, sa2, sa3;
    if (T + 1 < NTS) {
      const float* p = asrc + (T + 1) * BKS;
      sa0 = *(const float4*)(p);
      sa1 = *(const float4*)(p + 4);
      sa2 = *(const float4*)(p + 8);
      sa3 = *(const float4*)(p + 12);
    }
#pragma unroll
    for (int ss = 0; ss < 4; ++ss) {
      const int t32 = T * 4 + ss;
      __builtin_amdgcn_s_setprio(1);
#pragma unroll
      for (int mf = 0; mf < 3; ++mf) {
        const int row = mf * 16 + llo;
        bf16x8 af = *(const bf16x8*)(
            asr + ((row * 256 + (ss * 32 + lhi * 8) * 2) ^ ((row & 7) << 4)));
        acc[mf][0] = __builtin_amdgcn_mfma_f32_16x16x32_bf16(af, *(const bf16x8*)&rb[0], acc[mf][0], 0, 0, 0);
        acc[mf][1] = __builtin_amdgcn_mfma_f32_16x16x32_bf16(af, *(const bf16x8*)&rb[1], acc[mf][1], 0, 0, 0);
        acc[mf][2] = __builtin_amdgcn_mfma_f32_16x16x32_bf16(af, *(const bf16x8*)&rb[2], acc[mf][2], 0, 0, 0);
        acc[mf][3] = __builtin_amdgcn_mfma_f32_16x16x32_bf16(af, *(const bf16x8*)&rb[3], acc[mf][3], 0, 0, 0);
      }
      {
        const int row = 48 + llo;
        bf16x8 af = *(const bf16x8*)(
            asr + ((row * 256 + (ss * 32 + lhi * 8) * 2) ^ ((row & 7) << 4)));
#pragma unroll
        for (int nf = 0; nf < 4; ++nf) {
          acc[3][nf] = __builtin_amdgcn_mfma_f32_16x16x32_bf16(af, *(const bf16x8*)&rb[nf], acc[3][nf], 0, 0, 0);
          if (t32 + 1 < 32)   // refresh B right after last use
            rb[nf] = wt4[(size_t)(t32 + 1) * 2048 + bbase + nf * 64];
        }
      }
      __builtin_amdgcn_s_setprio(0);
    }
    // convert + write next A buffer, then lgkm-only barrier
    if (T + 1 < NTS) {
      char* asw = smem + ((T + 1) & 1) * ABUF;
      unsigned short o[16] = {f2bf(sa0.x), f2bf(sa0.y), f2bf(sa0.z), f2bf(sa0.w),
                              f2bf(sa1.x), f2bf(sa1.y), f2bf(sa1.z), f2bf(sa1.w),
                              f2bf(sa2.x), f2bf(sa2.y), f2bf(sa2.z), f2bf(sa2.w),
                              f2bf(sa3.x), f2bf(sa3.y), f2bf(sa3.z), f2bf(sa3.w)};
      *(u32x4*)(asw + wb0) = *(const u32x4*)&o[0];
      *(u32x4*)(asw + wb1) = *(const u32x4*)&o[8];
    }
    asm volatile("s_waitcnt lgkmcnt(0)" ::: "memory");
    __builtin_amdgcn_s_barrier();
  }

  // ---- epilogue 1: tanh + dot(v-slice) + 16-lane reduce -> sp[row][wid] ----
  {
    const float vv0 = v[wid * 64 +  0 + llo];
    const float vv1 = v[wid * 64 + 16 + llo];
    const float vv2 = v[wid * 64 + 32 + llo];
    const float vv3 = v[wid * 64 + 48 + llo];
#pragma unroll
    for (int mf = 0; mf < 4; ++mf) {
      float pr[4] = {0.f, 0.f, 0.f, 0.f};
#pragma unroll
      for (int r = 0; r < 4; ++r) {
        pr[r] += fast_tanh(acc[mf][0][r]) * vv0;
        pr[r] += fast_tanh(acc[mf][1][r]) * vv1;
        pr[r] += fast_tanh(acc[mf][2][r]) * vv2;
        pr[r] += fast_tanh(acc[mf][3][r]) * vv3;
      }
#pragma unroll
      for (int r = 0; r < 4; ++r) {
        float p = pr[r];
        p += __shfl_xor(p, 1, 64);
        p += __shfl_xor(p, 2, 64);
        p += __shfl_xor(p, 4, 64);
        p += __shfl_xor(p, 8, 64);
        if (llo == 0) sp[mf * 16 + lhi * 4 + r][wid] = p;
      }
    }
  }
  __syncthreads();

  // ---- epilogue 2: softmax over the 64 rows (wave 0) ----
  if (tid < BM) {
    float s = 0.f;
#pragma unroll
    for (int w = 0; w < 8; ++w) s += sp[tid][w];
    float mx = s;
#pragma unroll
    for (int mask = 1; mask < 64; mask <<= 1)
      mx = fmaxf(mx, __shfl_xor(mx, mask, 64));
    const float e = __builtin_amdgcn_exp2f((s - mx) * 1.442695040888963f);
    float sum = e;
#pragma unroll
    for (int mask = 1; mask < 64; mask <<= 1)
      sum += __shfl_xor(sum, mask, 64);
    attn[tid] = e * __builtin_amdgcn_rcpf(sum);
  }
  __syncthreads();

  // ---- epilogue 3: out = sum_s attn[s]*x[m0+s][:], 2-way s-split, MLP=4 ----
  const int c4 = tid & 255;
  const int sh = tid >> 8;
  const float* xg = x + ((size_t)m0 + sh * 32) * D_ + c4 * 4;
  f32x4 o0 = {0.f,0.f,0.f,0.f}, o1 = o0, o2 = o0, o3 = o0;
#pragma unroll
  for (int s = 0; s < 32; s += 4) {
    const float w0 = attn[sh * 32 + s + 0];
    const float w1 = attn[sh * 32 + s + 1];
    const float w2 = attn[sh * 32 + s + 2];
    const float w3 = attn[sh * 32 + s + 3];
    const float4 a0 = *(const float4*)(xg + (size_t)(s + 0) * D_);
    const float4 a1 = *(const float4*)(xg + (size_t)(s + 1) * D_);
    const float4 a2 = *(const float4*)(xg + (size_t)(s + 2) * D_);
    const float4 a3 = *(const float4*)(xg + (size_t)(s + 3) * D_);
    o0[0] += w0 * a0.x; o0[1] += w0 * a0.y; o0[2] += w0 * a0.z; o0[3] += w0 * a0.w;
    o1[0] += w1 * a1.x; o1[1] += w1 * a1.y; o1[2] += w1 * a1.z; o1[3] += w1 * a1.w;
    o2[0] += w2 * a2.x; o2[1] += w2 * a2.y; o2[2] += w2 * a2.z; o2[3] += w2 * a2.w;
    o3[0] += w3 * a3.x; o3[1] += w3 * a3.y; o3[2] += w3 * a3.z; o3[3] += w3 * a3.w;
  }
  f32x4 o;
#pragma unroll
  for (int j = 0; j < 4; ++j) o[j] = (o0[j] + o1[j]) + (o2[j] + o3[j]);
  if (sh == 1) xred[c4] = o;
  __syncthreads();
  if (sh == 0) {
    f32x4 o2b = xred[c4];
    float4 res = {o[0] + o2b[0], o[1] + o2b[1], o[2] + o2b[2], o[3] + o2b[3]};
    *(float4*)(out + (size_t)bt * D_ + c4 * 4) = res;
  }
}

extern "C" void kernel_launch(void* const* d_in, const int* in_sizes, int n_in,
                              void* d_out, int out_size, void* d_ws, size_t ws_size,
                              hipStream_t stream) {
  const float* x = (const float*)d_in[0];   // (16,64,64,1024) fp32
  const float* W = (const float*)d_in[1];   // (1024,512) fp32
  const float* v = (const float*)d_in[2];   // (512,) fp32
  float* out = (float*)d_out;               // (16,64,1024) fp32
  unsigned short* Wt = (unsigned short*)d_ws;  // 1 MB fragment-ordered bf16

  make_bfrag<<<dim3(32, PROJ_ / 32), 256, 0, stream>>>(W, Wt);
  fused_kernel<<<B_ * T1_, 512, 0, stream>>>(x, Wt, v, out);
}

// Round 9
// 128.929 us; speedup vs baseline: 1.6321x; 1.6321x over previous
//
#include <hip/hip_runtime.h>
#include <hip/hip_bf16.h>
#include <math.h>

#define B_    16
#define T1_   64
#define T2_   64
#define D_    1024
#define PROJ_ 512
#define BM    64
#define NKH   16                 // k-steps (of 32) per K-half
#define HALFK 512                // k per half

typedef __attribute__((ext_vector_type(8))) short bf16x8;
typedef __attribute__((ext_vector_type(4))) float f32x4;
typedef __attribute__((ext_vector_type(4))) unsigned int u32x4;

// RNE fp32->bf16, no NaN path (inputs are finite)
__device__ __forceinline__ unsigned short f2bf(float f) {
  unsigned int u = __builtin_bit_cast(unsigned int, f);
  u += 0x7FFFu + ((u >> 16) & 1u);
  return (unsigned short)(u >> 16);
}

// tanh(a) = 1 - 2/(exp(2a)+1); v_exp_f32 + v_rcp_f32, ~5 instr, |err|~1e-6
__device__ __forceinline__ float fast_tanh(float a) {
  float t = __builtin_amdgcn_exp2f(a * 2.885390081777927f);  // exp(2a)
  return 1.0f - 2.0f * __builtin_amdgcn_rcpf(t + 1.0f);
}

// ---------------------------------------------------------------------------
// Prep: Wt fragment-ordered bf16. 16B chunk index ((t32*32 + n16)*64 + lane)
// holds W[k][n], n = n16*16 + (lane&15), k = t32*32 + (lane>>4)*8 + j.
// ---------------------------------------------------------------------------
__global__ __launch_bounds__(256) void make_bfrag(
    const float* __restrict__ W, unsigned short* __restrict__ wt) {
  __shared__ float tile[32][33];
  const int t  = blockIdx.x;        // k-step 0..31
  const int np = blockIdx.y;        // n-pair 0..15
  const int tx = threadIdx.x & 31;
  const int ty = threadIdx.x >> 5;  // 0..7
#pragma unroll
  for (int i = 0; i < 4; ++i)
    tile[ty + i * 8][tx] =
        W[(size_t)(t * 32 + ty + i * 8) * PROJ_ + np * 32 + tx];
  __syncthreads();
  if (threadIdx.x < 128) {
    const int sub  = threadIdx.x >> 6;   // 0..1
    const int lane = threadIdx.x & 63;
    const int llo = lane & 15, lhi = lane >> 4;
    unsigned short o[8];
#pragma unroll
    for (int j = 0; j < 8; ++j)
      o[j] = f2bf(tile[lhi * 8 + j][sub * 16 + llo]);
    const int n16 = np * 2 + sub;
    *(u32x4*)(wt + ((size_t)(t * 32 + n16) * 64 + lane) * 8) = *(const u32x4*)o;
  }
}

// ---------------------------------------------------------------------------
// Fused: one (b,t1) group of 64 rows per 512-thread block (8 waves).
// scores = v . tanh(x @ W) via bf16 MFMA -> softmax(64) -> out = attn . x
// K processed in 2 halves. Per half: stage A (64x512, bf16, XOR-swizzled)
// into 64 KB LDS ONCE, then a BARRIER-FREE K-loop of 16 steps: each wave
// independently ds_reads its A-frags (LDS read-only => no hazard), loads
// B-frags from L2-resident fragment-ordered Wt, 16 MFMA per step.
// ~5 __syncthreads() total (vs 66 in the 2-phase structure that capped at
// the ~400-600 TF 2-barrier ceiling). 64 KB LDS -> 2 blocks/CU, 16 waves.
// ---------------------------------------------------------------------------
__global__ __launch_bounds__(512, 4) void fused_kernel(
    const float* __restrict__ x, const unsigned short* __restrict__ wt,
    const float* __restrict__ v, float* __restrict__ out) {
  __shared__ __align__(16) char smem[65536];      // A half-tile; epilogue overlays
  float (*sp)[9] = (float(*)[9])smem;             // 2304 B
  float* attn    = (float*)(smem + 2304);         // 256 B
  f32x4* xred    = (f32x4*)(smem + 2560);         // 4 KB

  const int tid  = threadIdx.x;
  const int lane = tid & 63;
  const int wid  = tid >> 6;            // 0..7 = 64-col n-slice
  const int llo  = lane & 15, lhi = lane >> 4;
  const int swz  = (llo & 7) << 4;      // per-lane A swizzle (row&7 == llo&7)
  const int bt   = blockIdx.x;
  const int m0   = bt * BM;

  f32x4 acc[4][4];
#pragma unroll
  for (int mf = 0; mf < 4; ++mf)
#pragma unroll
    for (int nf = 0; nf < 4; ++nf) acc[mf][nf] = (f32x4){0.f, 0.f, 0.f, 0.f};

  const u32x4* wt4 = (const u32x4*)wt;  // chunk idx (t32*32 + n16)*64 + lane
  const int bbase = (wid * 4) * 64 + lane;

  // B(t32=0) prefetch (latency covered by staging)
  u32x4 rb[4];
#pragma unroll
  for (int nf = 0; nf < 4; ++nf) rb[nf] = wt4[bbase + nf * 64];

  // ---- staging: half h of A -> LDS bf16, swizzled. 8 rounds x 32B/thread.
  // pair p = r*512+tid: row = p>>6 (one row per wave-round, coalesced 2KB),
  // pc = p&63; LDS byte = (row*1024 + pc*16) ^ ((row&7)<<4).
#define STAGE(H)                                                              \
  {                                                                           \
    _Pragma("unroll")                                                         \
    for (int r = 0; r < 8; ++r) {                                             \
      const int p = r * 512 + tid;                                            \
      const int row = p >> 6, pc = p & 63;                                    \
      const float* s = x + (size_t)(m0 + row) * D_ + (H) * HALFK + pc * 8;    \
      float4 a = *(const float4*)s;                                           \
      float4 b = *(const float4*)(s + 4);                                     \
      unsigned short o[8] = {f2bf(a.x), f2bf(a.y), f2bf(a.z), f2bf(a.w),      \
                             f2bf(b.x), f2bf(b.y), f2bf(b.z), f2bf(b.w)};     \
      const int db = (row * 1024 + pc * 16) ^ ((row & 7) << 4);               \
      *(u32x4*)(smem + db) = *(const u32x4*)o;                                \
    }                                                                         \
  }

  // ---- barrier-free K-loop over half H: 16 steps, wave-autonomous ----
#define KLOOP(H)                                                              \
  {                                                                           \
    _Pragma("unroll 2")                                                       \
    for (int ks = 0; ks < NKH; ++ks) {                                        \
      const int t32 = (H) * NKH + ks;                                         \
      const int kb = ks * 64 + lhi * 16;                                      \
      bf16x8 af0 = *(const bf16x8*)(smem + ((( 0 + llo) * 1024 + kb) ^ swz)); \
      bf16x8 af1 = *(const bf16x8*)(smem + (((16 + llo) * 1024 + kb) ^ swz)); \
      bf16x8 af2 = *(const bf16x8*)(smem + (((32 + llo) * 1024 + kb) ^ swz)); \
      bf16x8 af3 = *(const bf16x8*)(smem + (((48 + llo) * 1024 + kb) ^ swz)); \
      u32x4 rbn[4];                                                           \
      if (t32 + 1 < 32) {                                                     \
        _Pragma("unroll")                                                     \
        for (int nf = 0; nf < 4; ++nf)                                        \
          rbn[nf] = wt4[(size_t)(t32 + 1) * 2048 + bbase + nf * 64];          \
      }                                                                       \
      __builtin_amdgcn_s_setprio(1);                                          \
      _Pragma("unroll")                                                       \
      for (int nf = 0; nf < 4; ++nf) {                                        \
        bf16x8 bfr = *(const bf16x8*)&rb[nf];                                 \
        acc[0][nf] = __builtin_amdgcn_mfma_f32_16x16x32_bf16(af0, bfr, acc[0][nf], 0, 0, 0); \
        acc[1][nf] = __builtin_amdgcn_mfma_f32_16x16x32_bf16(af1, bfr, acc[1][nf], 0, 0, 0); \
        acc[2][nf] = __builtin_amdgcn_mfma_f32_16x16x32_bf16(af2, bfr, acc[2][nf], 0, 0, 0); \
        acc[3][nf] = __builtin_amdgcn_mfma_f32_16x16x32_bf16(af3, bfr, acc[3][nf], 0, 0, 0); \
      }                                                                       \
      __builtin_amdgcn_s_setprio(0);                                          \
      if (t32 + 1 < 32) {                                                     \
        _Pragma("unroll")                                                     \
        for (int nf = 0; nf < 4; ++nf) rb[nf] = rbn[nf];                      \
      }                                                                       \
    }                                                                         \
  }

  STAGE(0)
  __syncthreads();
  KLOOP(0)
  __syncthreads();        // all reads of half 0 done
  STAGE(1)
  __syncthreads();
  KLOOP(1)
  __syncthreads();        // A LDS free; epilogue overlays
#undef STAGE
#undef KLOOP

  // ---- epilogue 1: tanh + dot(v-slice) + 16-lane reduce -> sp[row][wid] ----
  {
    const float vv0 = v[wid * 64 +  0 + llo];
    const float vv1 = v[wid * 64 + 16 + llo];
    const float vv2 = v[wid * 64 + 32 + llo];
    const float vv3 = v[wid * 64 + 48 + llo];
#pragma unroll
    for (int mf = 0; mf < 4; ++mf) {
      float pr[4] = {0.f, 0.f, 0.f, 0.f};
#pragma unroll
      for (int r = 0; r < 4; ++r) {
        pr[r] += fast_tanh(acc[mf][0][r]) * vv0;
        pr[r] += fast_tanh(acc[mf][1][r]) * vv1;
        pr[r] += fast_tanh(acc[mf][2][r]) * vv2;
        pr[r] += fast_tanh(acc[mf][3][r]) * vv3;
      }
#pragma unroll
      for (int r = 0; r < 4; ++r) {
        float p = pr[r];
        p += __shfl_xor(p, 1, 64);
        p += __shfl_xor(p, 2, 64);
        p += __shfl_xor(p, 4, 64);
        p += __shfl_xor(p, 8, 64);
        if (llo == 0) sp[mf * 16 + lhi * 4 + r][wid] = p;
      }
    }
  }
  __syncthreads();

  // ---- epilogue 2: softmax over the 64 rows (wave 0) ----
  if (tid < BM) {
    float s = 0.f;
#pragma unroll
    for (int w = 0; w < 8; ++w) s += sp[tid][w];
    float mx = s;
#pragma unroll
    for (int mask = 1; mask < 64; mask <<= 1)
      mx = fmaxf(mx, __shfl_xor(mx, mask, 64));
    const float e = __builtin_amdgcn_exp2f((s - mx) * 1.442695040888963f);
    float sum = e;
#pragma unroll
    for (int mask = 1; mask < 64; mask <<= 1)
      sum += __shfl_xor(sum, mask, 64);
    attn[tid] = e * __builtin_amdgcn_rcpf(sum);
  }
  __syncthreads();

  // ---- epilogue 3: out = sum_s attn[s]*x[m0+s][:], 2-way s-split, MLP=4 ----
  const int c4 = tid & 255;
  const int sh = tid >> 8;
  const float* xg = x + ((size_t)m0 + sh * 32) * D_ + c4 * 4;
  f32x4 o0 = {0.f,0.f,0.f,0.f}, o1 = o0, o2 = o0, o3 = o0;
#pragma unroll
  for (int s = 0; s < 32; s += 4) {
    const float w0 = attn[sh * 32 + s + 0];
    const float w1 = attn[sh * 32 + s + 1];
    const float w2 = attn[sh * 32 + s + 2];
    const float w3 = attn[sh * 32 + s + 3];
    const float4 a0 = *(const float4*)(xg + (size_t)(s + 0) * D_);
    const float4 a1 = *(const float4*)(xg + (size_t)(s + 1) * D_);
    const float4 a2 = *(const float4*)(xg + (size_t)(s + 2) * D_);
    const float4 a3 = *(const float4*)(xg + (size_t)(s + 3) * D_);
    o0[0] += w0 * a0.x; o0[1] += w0 * a0.y; o0[2] += w0 * a0.z; o0[3] += w0 * a0.w;
    o1[0] += w1 * a1.x; o1[1] += w1 * a1.y; o1[2] += w1 * a1.z; o1[3] += w1 * a1.w;
    o2[0] += w2 * a2.x; o2[1] += w2 * a2.y; o2[2] += w2 * a2.z; o2[3] += w2 * a2.w;
    o3[0] += w3 * a3.x; o3[1] += w3 * a3.y; o3[2] += w3 * a3.z; o3[3] += w3 * a3.w;
  }
  f32x4 o;
#pragma unroll
  for (int j = 0; j < 4; ++j) o[j] = (o0[j] + o1[j]) + (o2[j] + o3[j]);
  if (sh == 1) xred[c4] = o;
  __syncthreads();
  if (sh == 0) {
    f32x4 o2b = xred[c4];
    float4 res = {o[0] + o2b[0], o[1] + o2b[1], o[2] + o2b[2], o[3] + o2b[3]};
    *(float4*)(out + (size_t)bt * D_ + c4 * 4) = res;
  }
}

extern "C" void kernel_launch(void* const* d_in, const int* in_sizes, int n_in,
                              void* d_out, int out_size, void* d_ws, size_t ws_size,
                              hipStream_t stream) {
  const float* x = (const float*)d_in[0];   // (16,64,64,1024) fp32
  const float* W = (const float*)d_in[1];   // (1024,512) fp32
  const float* v = (const float*)d_in[2];   // (512,) fp32
  float* out = (float*)d_out;               // (16,64,1024) fp32
  unsigned short* Wt = (unsigned short*)d_ws;  // 1 MB fragment-ordered bf16

  make_bfrag<<<dim3(32, PROJ_ / 32), 256, 0, stream>>>(W, Wt);
  fused_kernel<<<B_ * T1_, 512, 0, stream>>>(x, Wt, v, out);
}